// Round 3
// baseline (262.334 us; speedup 1.0000x reference)
//
#include <hip/hip_runtime.h>
#include <hip/hip_bf16.h>

// Problem constants
#define B_   4
#define S_   2048
#define H_   1024
#define NH_  16
#define HD_  64
#define M_   8192   // B_*S_
#define K_   1024

using bf16x8 = __bf16 __attribute__((ext_vector_type(8)));
using f32x4  = float __attribute__((ext_vector_type(4)));

__device__ inline f32x4 mfma16(bf16x8 a, bf16x8 b, f32x4 c) {
    return __builtin_amdgcn_mfma_f32_16x16x32_bf16(a, b, c, 0, 0, 0);
}

__device__ inline unsigned short f2bf(float f) {
    __hip_bfloat16 h = __float2bfloat16(f);
    return *reinterpret_cast<unsigned short*>(&h);
}

// pack 2 f32 -> 2 bf16 in one u32
__device__ inline unsigned cvt_pk_bf16(float lo, float hi) {
    unsigned r;
    asm("v_cvt_pk_bf16_f32 %0, %1, %2" : "=v"(r) : "v"(lo), "v"(hi));
    return r;
}

// async global->LDS, 16B per lane; LDS dest = wave-uniform base + lane*16
__device__ inline void gload_lds16(const unsigned short* g, unsigned short* l) {
    __builtin_amdgcn_global_load_lds(
        (const __attribute__((address_space(1))) void*)g,
        (__attribute__((address_space(3))) void*)l, 16, 0, 0);
}

#define EXP2F(x) __builtin_amdgcn_exp2f(x)

// ---------------------------------------------------------------------------
// Workspace layout (ushort elements unless noted):
//   xb   @ 0          (M*K)  bf16 x   [reused as attn-out]
//   wqb  @ 8388608    wkb @ 9437184   wvb @ 10485760   wob @ 11534336
//   qbuf @ 12582912   (B,NH,S,HD) bf16, RoPE'd, pre-scaled by 0.125*log2(e)
//   kbuf @ 20971520   (B,NH,S,HD) bf16, RoPE'd
//   vtb  @ 29360128   (B,NH,HD,S) bf16 (transposed V)
//   cosb @ 37748736 (f32, 65536); sinb follows; biasb (f32, 8192) follows
// ---------------------------------------------------------------------------

__global__ __launch_bounds__(256) void prep_convert(
    const float* __restrict__ x,  const float* __restrict__ wq,
    const float* __restrict__ wk, const float* __restrict__ wv,
    const float* __restrict__ wo, unsigned short* __restrict__ ws)
{
    size_t u = (size_t)blockIdx.x * 256 + threadIdx.x;   // 3,145,728 units of 4 floats
    const float* src; unsigned short* dst; size_t off;
    if (u < 2097152)      { src = x;  dst = ws;            off = u * 4; }
    else if (u < 2359296) { src = wq; dst = ws + 8388608;  off = (u - 2097152) * 4; }
    else if (u < 2621440) { src = wk; dst = ws + 9437184;  off = (u - 2359296) * 4; }
    else if (u < 2883584) { src = wv; dst = ws + 10485760; off = (u - 2621440) * 4; }
    else                  { src = wo; dst = ws + 11534336; off = (u - 2883584) * 4; }
    float4 v = *reinterpret_cast<const float4*>(src + off);
    ushort4 o;
    o.x = f2bf(v.x); o.y = f2bf(v.y); o.z = f2bf(v.z); o.w = f2bf(v.w);
    *reinterpret_cast<ushort4*>(dst + off) = o;
}

// cos/sin tables [S][32] + additive mask bias (0 / -inf) f32[B*S]
__global__ __launch_bounds__(256) void rope_table(
    float* __restrict__ cosb, float* __restrict__ sinb,
    const int* __restrict__ mask, float* __restrict__ biasb)
{
    int idx = blockIdx.x * 256 + threadIdx.x;   // 65536
    int pos = idx >> 5, i = idx & 31;
    float inv = expf(-(float)(2 * i) * (9.210340371976184f / 64.0f));
    float ang = (float)pos * inv;
    cosb[idx] = cosf(ang);
    sinb[idx] = sinf(ang);
    if (idx < B_ * S_)
        biasb[idx] = mask[idx] ? 0.f : -__builtin_inff();
}

// ---------------------------------------------------------------------------
// GEMM: C[M x 1024] = A[M x 1024] * W^T   (W row-major [1024 x 1024])
// 128x128 tile, 4 waves of 64x64, BK=64, global_load_lds staging with
// inverse-swizzled source (linear LDS dest) + XOR-swizzled ds_read_b128.
// ---------------------------------------------------------------------------
template<int EPI>
__global__ __launch_bounds__(256) void gemm_bt(
    const unsigned short* __restrict__ A,
    const unsigned short* __restrict__ W,
    void* __restrict__ outp,
    const float* __restrict__ cosb, const float* __restrict__ sinb,
    float scale)
{
    __shared__ alignas(16) unsigned short Al[128 * 64];
    __shared__ alignas(16) unsigned short Bl[128 * 64];

    const int t = threadIdx.x;
    const int l = t & 63;
    const int w = t >> 6;
    const int lane_r = l & 15, lane_g = l >> 4;
    const int bn = blockIdx.x, bm = blockIdx.y;
    const size_t rowbase = (size_t)bm * 128;
    const int colbase = bn * 128;
    const int wm = (w >> 1) * 64, wn = (w & 1) * 64;

    // gload geometry: lane covers row base+l/8, LDS slot l%8.
    // Content swizzle via source col-block = (l&7) ^ (l>>3).
    const int glrow  = l >> 3;
    const int glslot = (l & 7) ^ glrow;

    f32x4 zero4 = {0.f, 0.f, 0.f, 0.f};
    f32x4 acc[4][4];
#pragma unroll
    for (int a = 0; a < 4; a++)
#pragma unroll
        for (int b2 = 0; b2 < 4; b2++) acc[a][b2] = zero4;

    for (int k0 = 0; k0 < K_; k0 += 64) {
#pragma unroll
        for (int i = 0; i < 4; i++) {
            int rbase = i * 32 + w * 8;
            int row = rbase + glrow;
            gload_lds16(A + (rowbase + row) * K_ + k0 + glslot * 8, &Al[rbase * 64]);
            gload_lds16(W + (size_t)(colbase + row) * K_ + k0 + glslot * 8, &Bl[rbase * 64]);
        }
        __syncthreads();   // vmcnt drained before barrier -> tiles visible

        bf16x8 af[4][2], bfr[4][2];
#pragma unroll
        for (int mt = 0; mt < 4; mt++)
#pragma unroll
            for (int kk = 0; kk < 2; kk++) {
                int rowa = wm + mt * 16 + lane_r;
                int offa = (rowa * 128 + kk * 64 + lane_g * 16) ^ ((rowa & 7) << 4);
                af[mt][kk] = *reinterpret_cast<const bf16x8*>((const char*)Al + offa);
                int rowb = wn + mt * 16 + lane_r;
                int offb = (rowb * 128 + kk * 64 + lane_g * 16) ^ ((rowb & 7) << 4);
                bfr[mt][kk] = *reinterpret_cast<const bf16x8*>((const char*)Bl + offb);
            }
#pragma unroll
        for (int mt = 0; mt < 4; mt++)
#pragma unroll
            for (int nt = 0; nt < 4; nt++) {
                acc[mt][nt] = mfma16(af[mt][0], bfr[nt][0], acc[mt][nt]);
                acc[mt][nt] = mfma16(af[mt][1], bfr[nt][1], acc[mt][nt]);
            }
        __syncthreads();   // compute done before next iter's loads overwrite
    }

    // Epilogue.  D-layout: row = (l>>4)*4 + i, col = l&15 within each 16x16.
#pragma unroll
    for (int mt = 0; mt < 4; mt++) {
#pragma unroll
        for (int nt = 0; nt < 4; nt++) {
            if constexpr (EPI == 2) {
                float* out = (float*)outp;
#pragma unroll
                for (int i = 0; i < 4; i++) {
                    size_t r = rowbase + wm + mt * 16 + lane_g * 4 + i;
                    int n = colbase + wn + nt * 16 + lane_r;
                    out[r * 1024 + n] = acc[mt][nt][i];
                }
            } else if constexpr (EPI == 0) {
                unsigned short* out = (unsigned short*)outp;
#pragma unroll
                for (int i = 0; i < 4; i++) {
                    size_t r = rowbase + wm + mt * 16 + lane_g * 4 + i;
                    int n = colbase + wn + nt * 16 + lane_r;
                    int b   = (int)(r >> 11);
                    int pos = (int)(r & 2047);
                    int h = n >> 6, d = n & 63;
                    float cv = cosb[pos * 32 + (d >> 1)];
                    float sv = sinb[pos * 32 + (d >> 1)];
                    float val = acc[mt][nt][i];
                    float partner = __shfl_xor(val, 1);
                    float o = (d & 1) ? (partner * sv + val * cv)
                                      : (val * cv - partner * sv);
                    o *= scale;
                    out[(((size_t)(b * NH_ + h)) * S_ + pos) * 64 + d] = f2bf(o);
                }
            } else { // EPI == 1 : transposed V
                unsigned short* out = (unsigned short*)outp;
                size_t rr = rowbase + wm + mt * 16 + lane_g * 4;
                int n = colbase + wn + nt * 16 + lane_r;
                int b   = (int)(rr >> 11);
                int pos = (int)(rr & 2047);
                int h = n >> 6, d = n & 63;
                ushort4 o;
                o.x = f2bf(acc[mt][nt][0]); o.y = f2bf(acc[mt][nt][1]);
                o.z = f2bf(acc[mt][nt][2]); o.w = f2bf(acc[mt][nt][3]);
                *reinterpret_cast<ushort4*>(
                    out + (((size_t)(b * NH_ + h)) * 64 + d) * S_ + pos) = o;
            }
        }
    }
}

// ---------------------------------------------------------------------------
// Flash attention, swapped-operand form, Q=32 rows per wave (2 q-sub-blocks):
//   S^T = mfma(K, Q)     lane owns one q-row (q = lane&15) per sub-block
//   O^T = mfma(V^T, P^T) acc col = q
// K/V staged via source-swizzled global_load_lds (shared by both q-blocks),
// exp2 domain, additive bias from global, defer-max, packed P writes.
// Block = 4 waves x 32 q = 128 q-rows; KVBLK = 64; grid = 64 bh x 16 qt.
// ---------------------------------------------------------------------------
__global__ __launch_bounds__(256) void attn_fwd(
    const unsigned short* __restrict__ qb, const unsigned short* __restrict__ kb,
    const unsigned short* __restrict__ vt, const float* __restrict__ biasb,
    unsigned short* __restrict__ ao)
{
    __shared__ alignas(16) unsigned short Kl[64 * 64];
    __shared__ alignas(16) unsigned short Vl[64 * 64];
    __shared__ alignas(16) unsigned short Pl[8][16 * 64];

    // XCD-clustering swizzle (bijective: 1024 % 8 == 0): 8 bh per XCD.
    const int bid = blockIdx.x;
    const int xcd = bid & 7, idx = bid >> 3;
    const int bh = xcd * 8 + (idx >> 4);
    const int qt = idx & 15;
    const int b = bh >> 4, h = bh & 15;

    const int t = threadIdx.x, l = t & 63, w = t >> 6;
    const int lane_r = l & 15, lane_g = l >> 4;
    const int glrow  = l >> 3;
    const int glslot = (l & 7) ^ glrow;

    const unsigned short* qp = qb + (size_t)bh * S_ * 64;
    const unsigned short* kp = kb + (size_t)bh * S_ * 64;
    const unsigned short* vp = vt + (size_t)bh * 64 * S_;
    const float* bp = biasb + (size_t)b * S_;

    // Q fragments (pre-scaled by 0.125*log2e in projection epilogue)
    bf16x8 qf[2][2];
#pragma unroll
    for (int qs = 0; qs < 2; qs++) {
        int qrow = qt * 128 + w * 32 + qs * 16 + lane_r;
        qf[qs][0] = *reinterpret_cast<const bf16x8*>(qp + (size_t)qrow * 64 + lane_g * 8);
        qf[qs][1] = *reinterpret_cast<const bf16x8*>(qp + (size_t)qrow * 64 + 32 + lane_g * 8);
    }

    f32x4 zero4 = {0.f, 0.f, 0.f, 0.f};
    float m_run[2] = {-3.0e38f, -3.0e38f}, l_run[2] = {0.f, 0.f};
    f32x4 oacc[2][4];
#pragma unroll
    for (int qs = 0; qs < 2; qs++)
#pragma unroll
        for (int i = 0; i < 4; i++) oacc[qs][i] = zero4;

    for (int kt = 0; kt < 32; kt++) {
        __syncthreads();   // previous tile's LDS reads done
#pragma unroll
        for (int i = 0; i < 2; i++) {
            int rbase = i * 32 + w * 8;
            int row = rbase + glrow;
            gload_lds16(kp + (size_t)(kt * 64 + row) * 64 + glslot * 8, &Kl[rbase * 64]);
            gload_lds16(vp + (size_t)row * S_ + kt * 64 + glslot * 8, &Vl[rbase * 64]);
        }
        __syncthreads();   // loads landed (vmcnt drained before barrier)

        // S^T = K x Q for both q-sub-blocks (K fragments shared)
        f32x4 s[2][4];
        __builtin_amdgcn_s_setprio(1);
#pragma unroll
        for (int nt = 0; nt < 4; nt++) {
            int row = nt * 16 + lane_r;
            int off0 = (row * 128 + lane_g * 16) ^ ((row & 7) << 4);
            bf16x8 k0v = *reinterpret_cast<const bf16x8*>((const char*)Kl + off0);
            bf16x8 k1v = *reinterpret_cast<const bf16x8*>((const char*)Kl + (off0 ^ 64));
            s[0][nt] = mfma16(k0v, qf[0][0], zero4);
            s[0][nt] = mfma16(k1v, qf[0][1], s[0][nt]);
            s[1][nt] = mfma16(k0v, qf[1][0], zero4);
            s[1][nt] = mfma16(k1v, qf[1][1], s[1][nt]);
        }
        __builtin_amdgcn_s_setprio(0);

        // additive mask bias (broadcast float4 from L2-resident table)
#pragma unroll
        for (int nt = 0; nt < 4; nt++) {
            float4 bv = *reinterpret_cast<const float4*>(bp + kt * 64 + nt * 16 + lane_g * 4);
#pragma unroll
            for (int qs = 0; qs < 2; qs++) {
                s[qs][nt][0] += bv.x; s[qs][nt][1] += bv.y;
                s[qs][nt][2] += bv.z; s[qs][nt][3] += bv.w;
            }
        }

        // softmax + P write per q-sub-block
#pragma unroll
        for (int qs = 0; qs < 2; qs++) {
            float pmax = fmaxf(fmaxf(s[qs][0][0], s[qs][0][1]), fmaxf(s[qs][0][2], s[qs][0][3]));
#pragma unroll
            for (int nt = 1; nt < 4; nt++)
                pmax = fmaxf(pmax, fmaxf(fmaxf(s[qs][nt][0], s[qs][nt][1]),
                                         fmaxf(s[qs][nt][2], s[qs][nt][3])));
            pmax = fmaxf(pmax, __shfl_xor(pmax, 16));
            pmax = fmaxf(pmax, __shfl_xor(pmax, 32));
            if (!__all(pmax <= m_run[qs] + 8.0f)) {   // defer-max (T13)
                float mnew = fmaxf(m_run[qs], pmax);
                float sc = EXP2F(m_run[qs] - mnew);
                m_run[qs] = mnew;
                l_run[qs] *= sc;
#pragma unroll
                for (int nt = 0; nt < 4; nt++)
#pragma unroll
                    for (int i = 0; i < 4; i++) oacc[qs][nt][i] *= sc;
            }
            float rs = 0.f;
            f32x4 p[4];
#pragma unroll
            for (int nt = 0; nt < 4; nt++)
#pragma unroll
                for (int i = 0; i < 4; i++) {
                    float pv = EXP2F(s[qs][nt][i] - m_run[qs]);
                    p[nt][i] = pv;
                    rs += pv;
                }
            rs += __shfl_xor(rs, 16);
            rs += __shfl_xor(rs, 32);
            l_run[qs] += rs;

            unsigned short* pl = (unsigned short*)Pl[w * 2 + qs];
#pragma unroll
            for (int nt = 0; nt < 4; nt++) {
                uint2 u;
                u.x = cvt_pk_bf16(p[nt][0], p[nt][1]);
                u.y = cvt_pk_bf16(p[nt][2], p[nt][3]);
                int off = (lane_r * 128 + (nt * 16 + lane_g * 4) * 2) ^ ((lane_r & 7) << 4);
                *reinterpret_cast<uint2*>((char*)pl + off) = u;
            }
        }
        asm volatile("" ::: "memory");

        // P^T B-fragments
        int pboff = (lane_r * 128 + lane_g * 16) ^ ((lane_r & 7) << 4);
        bf16x8 pb[2][2];
#pragma unroll
        for (int qs = 0; qs < 2; qs++) {
            const char* pl = (const char*)Pl[w * 2 + qs];
            pb[qs][0] = *reinterpret_cast<const bf16x8*>(pl + pboff);
            pb[qs][1] = *reinterpret_cast<const bf16x8*>(pl + (pboff ^ 64));
        }

        // O^T += V^T x P^T (V fragments shared)
        __builtin_amdgcn_s_setprio(1);
#pragma unroll
        for (int nt = 0; nt < 4; nt++) {
            int row = nt * 16 + lane_r;
            int off0 = (row * 128 + lane_g * 16) ^ ((row & 7) << 4);
            bf16x8 v0 = *reinterpret_cast<const bf16x8*>((const char*)Vl + off0);
            bf16x8 v1 = *reinterpret_cast<const bf16x8*>((const char*)Vl + (off0 ^ 64));
#pragma unroll
            for (int qs = 0; qs < 2; qs++) {
                oacc[qs][nt] = mfma16(v0, pb[qs][0], oacc[qs][nt]);
                oacc[qs][nt] = mfma16(v1, pb[qs][1], oacc[qs][nt]);
            }
        }
        __builtin_amdgcn_s_setprio(0);
    }

    // finalize: lane holds d = nt*16+lane_g*4+i for q-row lane_r of each qs
#pragma unroll
    for (int qs = 0; qs < 2; qs++) {
        float rl = 1.0f / l_run[qs];
        size_t orow = (size_t)b * S_ + qt * 128 + w * 32 + qs * 16 + lane_r;
        unsigned short* aor = ao + orow * 1024 + h * 64;
#pragma unroll
        for (int nt = 0; nt < 4; nt++) {
            ushort4 o;
            o.x = f2bf(oacc[qs][nt][0] * rl); o.y = f2bf(oacc[qs][nt][1] * rl);
            o.z = f2bf(oacc[qs][nt][2] * rl); o.w = f2bf(oacc[qs][nt][3] * rl);
            *reinterpret_cast<ushort4*>(aor + nt * 16 + lane_g * 4) = o;
        }
    }
}

// ---------------------------------------------------------------------------
extern "C" void kernel_launch(void* const* d_in, const int* in_sizes, int n_in,
                              void* d_out, int out_size, void* d_ws, size_t ws_size,
                              hipStream_t stream)
{
    const float* x  = (const float*)d_in[0];
    const float* wq = (const float*)d_in[1];
    const float* wk = (const float*)d_in[2];
    const float* wv = (const float*)d_in[3];
    const float* wo = (const float*)d_in[4];
    const int* mask = (const int*)d_in[5];

    unsigned short* ws   = (unsigned short*)d_ws;
    unsigned short* xb   = ws;                 // M*K bf16; reused as attn-out
    unsigned short* wqb  = ws + 8388608;
    unsigned short* wkb  = ws + 9437184;
    unsigned short* wvb  = ws + 10485760;
    unsigned short* wob  = ws + 11534336;
    unsigned short* qbuf = ws + 12582912;
    unsigned short* kbuf = ws + 20971520;
    unsigned short* vtb  = ws + 29360128;
    float* cosb  = (float*)(ws + 37748736);
    float* sinb  = cosb + 65536;
    float* biasb = sinb + 65536;
    unsigned short* aob = xb;                  // alias: xb dead after V GEMM

    prep_convert<<<12288, 256, 0, stream>>>(x, wq, wk, wv, wo, ws);
    rope_table<<<256, 256, 0, stream>>>(cosb, sinb, mask, biasb);

    dim3 ggrid(8, 64);
    // Q scale = (1/sqrt(64)) * log2(e): softmax runs in exp2 domain
    gemm_bt<0><<<ggrid, 256, 0, stream>>>(xb, wqb, qbuf, cosb, sinb, 0.18033688089184827f);
    gemm_bt<0><<<ggrid, 256, 0, stream>>>(xb, wkb, kbuf, cosb, sinb, 1.0f);
    gemm_bt<1><<<ggrid, 256, 0, stream>>>(xb, wvb, vtb, nullptr, nullptr, 1.0f);

    attn_fwd<<<1024, 256, 0, stream>>>(qbuf, kbuf, vtb, biasb, aob);

    gemm_bt<2><<<ggrid, 256, 0, stream>>>(aob, wob, d_out, nullptr, nullptr, 1.0f);
}